// Round 6
// baseline (190.206 us; speedup 1.0000x reference)
//
#include <hip/hip_runtime.h>
#include <hip/hip_cooperative_groups.h>

namespace cg = cooperative_groups;

#define N  35
#define E  (N*N)
#define C1 256
#define C2 256
#define C3 128
#define NBLK 512
#define NTHR 256

// Workspace layout (floats):
//   h1   @ 0     : 35*256 = 8960
//   agg2 @ 8960  : 35*256 = 8960   (zeroed in phase 0;
//   agg3 @ 17920 : 35*128 = 4480    hold PRE-activation. bias+relu applied at read.)

// ======================= Fused cooperative kernel =======================
__global__ __launch_bounds__(NTHR, 2) void k_fused(
    const float* __restrict__ x,     const float* __restrict__ ea,
    const float* __restrict__ nn1w,  const float* __restrict__ nn1b,
    const float* __restrict__ w2,    const float* __restrict__ b2,
    const float* __restrict__ w3,    const float* __restrict__ b3,
    const float* __restrict__ root1, const float* __restrict__ bias1,
    const float* __restrict__ root2, const float* __restrict__ bias2,
    const float* __restrict__ root3, const float* __restrict__ bias3,
    float* __restrict__ h1, float* __restrict__ agg2, float* __restrict__ agg3,
    float* __restrict__ out)
{
    cg::grid_group grid = cg::this_grid();
    const int bid = blockIdx.x;
    const int tid = threadIdx.x;

    __shared__ float ea_s[N * 8];   // row-padded to 8: float4+float2 reads
    __shared__ float h_s[N * 8];

    // ===== Phase 0: layer1 (blocks 0..34) || zero aggs (blocks 35+) =====
    if (bid < N) {
        const int j = bid, o = tid;
        float w[6];
#pragma unroll
        for (int v = 0; v < 6; ++v) w[v] = nn1w[v * C1 + o];
        const float b = nn1b[o];
        float acc = 0.f;
        for (int i = 0; i < N; ++i) {
            float p = b;
#pragma unroll
            for (int v = 0; v < 6; ++v) p = fmaf(ea[(i * N + j) * 6 + v], w[v], p);
            acc = fmaf(x[i], fmaxf(p, 0.f), acc);
        }
        float s = acc * (1.f / N) + x[j] * root1[o] + bias1[o];
        h1[j * C1 + o] = fmaxf(s, 0.f);
    } else {
        int t = (bid - N) * NTHR + tid;
        if (t < 8960 + 4480) agg2[t] = 0.f;   // agg2,agg3 contiguous
    }
    grid.sync();

    // ===== Phase 1: layer2 — 1120 msg units (8c) + 280 root units (32c) =====
    for (int vb = bid; vb < N * 40; vb += NBLK) {
        const int j     = vb % N;
        const int chunk = vb / N;      // block-uniform
        const int o     = tid;
        if (chunk < 32) {
            const int c0 = chunk * 8;
            __syncthreads();           // protect LDS from previous unit's readers
            if (o < N * 6) { int i = o / 6, v = o % 6; ea_s[i * 8 + v] = ea[(i * N + j) * 6 + v]; }
            for (int t = o; t < N * 8; t += NTHR) { int i = t >> 3, cc = t & 7; h_s[t] = h1[i * C1 + c0 + cc]; }
            __syncthreads();

            float wv[8][6], bb[8], acc[8];
#pragma unroll
            for (int cc = 0; cc < 8; ++cc) {
                int col = (c0 + cc) * C2 + o;
#pragma unroll
                for (int v = 0; v < 6; ++v) wv[cc][v] = w2[v * (C1 * C2) + col];
                bb[cc] = b2[col];
                acc[cc] = 0.f;
            }
#pragma unroll 5
            for (int i = 0; i < N; ++i) {
                const float4 ef = *(const float4*)&ea_s[i * 8];
                const float2 eg = *(const float2*)&ea_s[i * 8 + 4];
                const float4 ha = *(const float4*)&h_s[i * 8];
                const float4 hb = *(const float4*)&h_s[i * 8 + 4];
                const float hv[8] = {ha.x, ha.y, ha.z, ha.w, hb.x, hb.y, hb.z, hb.w};
#pragma unroll
                for (int cc = 0; cc < 8; ++cc) {
                    float p = fmaf(ef.x, wv[cc][0], bb[cc]);
                    p = fmaf(ef.y, wv[cc][1], p);
                    p = fmaf(ef.z, wv[cc][2], p);
                    p = fmaf(ef.w, wv[cc][3], p);
                    p = fmaf(eg.x, wv[cc][4], p);
                    p = fmaf(eg.y, wv[cc][5], p);
                    p = fmaxf(p, 0.f);
                    acc[cc] = fmaf(hv[cc], p, acc[cc]);
                }
            }
            float s = 0.f;
#pragma unroll
            for (int cc = 0; cc < 8; ++cc) s += acc[cc];
            atomicAdd(&agg2[j * C2 + o], s * (1.f / N));
        } else {
            const int c0 = (chunk - 32) * 32;
            float s = 0.f;
#pragma unroll 8
            for (int c = c0; c < c0 + 32; ++c)
                s = fmaf(h1[j * C1 + c], root2[c * C2 + o], s);
            atomicAdd(&agg2[j * C2 + o], s);
        }
    }
    grid.sync();

    // ===== Phase 2: layer3 — 1120 msg units (8c) + 140 root units (64c) =====
    for (int vb = bid; vb < N * 36; vb += NBLK) {
        const int j     = vb % N;
        const int chunk = vb / N;
        const int o     = tid & (C3 - 1);
        const int half  = tid >> 7;        // wave-uniform
        if (chunk < 32) {
            const int c0 = chunk * 8;
            __syncthreads();
            if (tid < N * 6) { int i = tid / 6, v = tid % 6; ea_s[i * 8 + v] = ea[(i * N + j) * 6 + v]; }
            for (int t = tid; t < N * 8; t += NTHR) {
                int i = t >> 3, cc = t & 7;
                int c = c0 + cc;
                h_s[t] = fmaxf(agg2[i * C2 + c] + bias2[c], 0.f);
            }
            __syncthreads();

            float wv[8][6], bb[8], acc[8];
#pragma unroll
            for (int cc = 0; cc < 8; ++cc) {
                int col = (c0 + cc) * C3 + o;
#pragma unroll
                for (int v = 0; v < 6; ++v) wv[cc][v] = w3[v * (C2 * C3) + col];
                bb[cc] = b3[col];
                acc[cc] = 0.f;
            }
            const int ibeg = half ? 18 : 0;
            const int iend = half ? N  : 18;
            for (int i = ibeg; i < iend; ++i) {
                const float4 ef = *(const float4*)&ea_s[i * 8];
                const float2 eg = *(const float2*)&ea_s[i * 8 + 4];
                const float4 ha = *(const float4*)&h_s[i * 8];
                const float4 hb = *(const float4*)&h_s[i * 8 + 4];
                const float hv[8] = {ha.x, ha.y, ha.z, ha.w, hb.x, hb.y, hb.z, hb.w};
#pragma unroll
                for (int cc = 0; cc < 8; ++cc) {
                    float p = fmaf(ef.x, wv[cc][0], bb[cc]);
                    p = fmaf(ef.y, wv[cc][1], p);
                    p = fmaf(ef.z, wv[cc][2], p);
                    p = fmaf(ef.w, wv[cc][3], p);
                    p = fmaf(eg.x, wv[cc][4], p);
                    p = fmaf(eg.y, wv[cc][5], p);
                    p = fmaxf(p, 0.f);
                    acc[cc] = fmaf(hv[cc], p, acc[cc]);
                }
            }
            float s = 0.f;
#pragma unroll
            for (int cc = 0; cc < 8; ++cc) s += acc[cc];
            atomicAdd(&agg3[j * C3 + o], s * (1.f / N));
        } else {
            const int c0 = (chunk - 32) * 64 + half * 32;
            float s = 0.f;
#pragma unroll 8
            for (int c = c0; c < c0 + 32; ++c) {
                float hv = fmaxf(agg2[j * C2 + c] + bias2[c], 0.f);
                s = fmaf(hv, root3[c * C3 + o], s);
            }
            atomicAdd(&agg3[j * C3 + o], s);
        }
    }
    grid.sync();

    // ===== Phase 3: CBT pairwise L1, h3 = relu(agg3+bias3) on the fly =====
    for (int t = bid * NTHR + tid; t < E; t += NBLK * NTHR) {
        int i = t / N, j = t % N;
        float acc = 0.f;
#pragma unroll
        for (int f = 0; f < C3 / 4; ++f) {
            float4 a  = *(const float4*)&agg3[i * C3 + f * 4];
            float4 b  = *(const float4*)&agg3[j * C3 + f * 4];
            float4 bi = *(const float4*)&bias3[f * 4];
            float ax = fmaxf(a.x + bi.x, 0.f), bx = fmaxf(b.x + bi.x, 0.f);
            float ay = fmaxf(a.y + bi.y, 0.f), by = fmaxf(b.y + bi.y, 0.f);
            float az = fmaxf(a.z + bi.z, 0.f), bz = fmaxf(b.z + bi.z, 0.f);
            float aw = fmaxf(a.w + bi.w, 0.f), bw = fmaxf(b.w + bi.w, 0.f);
            acc += fabsf(bx - ax) + fabsf(by - ay) + fabsf(bz - az) + fabsf(bw - aw);
        }
        out[t] = acc;
    }
}

// ======================= Fallback path (proven 43.7us) =======================
__global__ __launch_bounds__(C1) void k_layer1(
    const float* __restrict__ x, const float* __restrict__ ea,
    const float* __restrict__ nn1w, const float* __restrict__ nn1b,
    const float* __restrict__ root1, const float* __restrict__ bias1,
    float* __restrict__ h1, float* __restrict__ aggz)
{
    for (int t = blockIdx.x * blockDim.x + threadIdx.x; t < 8960 + 4480;
         t += gridDim.x * blockDim.x)
        aggz[t] = 0.f;

    int j = blockIdx.x;
    int o = threadIdx.x;
    float w[6];
#pragma unroll
    for (int v = 0; v < 6; ++v) w[v] = nn1w[v * C1 + o];
    float b = nn1b[o];
    float acc = 0.f;
    for (int i = 0; i < N; ++i) {
        float p = b;
#pragma unroll
        for (int v = 0; v < 6; ++v) p = fmaf(ea[(i * N + j) * 6 + v], w[v], p);
        acc = fmaf(x[i], fmaxf(p, 0.f), acc);
    }
    float s = acc * (1.f / N) + x[j] * root1[o] + bias1[o];
    h1[j * C1 + o] = fmaxf(s, 0.f);
}

__global__ __launch_bounds__(256) void k_l2(
    const float* __restrict__ ea,
    const float* __restrict__ w2, const float* __restrict__ b2,
    const float* __restrict__ h1, const float* __restrict__ root2,
    float* __restrict__ agg2)
{
    const int j     = blockIdx.x % N;
    const int chunk = blockIdx.x / N;
    const int o     = threadIdx.x;

    if (chunk < 32) {
        const int c0 = chunk * 8;
        __shared__ float ea_s[N * 8];
        __shared__ float h1_s[N * 8];
        if (o < N * 6) { int i = o / 6, v = o % 6; ea_s[i * 8 + v] = ea[(i * N + j) * 6 + v]; }
        for (int t = o; t < N * 8; t += 256) { int i = t >> 3, cc = t & 7; h1_s[t] = h1[i * C1 + c0 + cc]; }
        __syncthreads();

        float wv[8][6], bb[8], acc[8];
#pragma unroll
        for (int cc = 0; cc < 8; ++cc) {
            int col = (c0 + cc) * C2 + o;
#pragma unroll
            for (int v = 0; v < 6; ++v) wv[cc][v] = w2[v * (C1 * C2) + col];
            bb[cc] = b2[col];
            acc[cc] = 0.f;
        }
#pragma unroll 5
        for (int i = 0; i < N; ++i) {
            const float4 ef = *(const float4*)&ea_s[i * 8];
            const float2 eg = *(const float2*)&ea_s[i * 8 + 4];
            const float4 ha = *(const float4*)&h1_s[i * 8];
            const float4 hb = *(const float4*)&h1_s[i * 8 + 4];
            const float hv[8] = {ha.x, ha.y, ha.z, ha.w, hb.x, hb.y, hb.z, hb.w};
#pragma unroll
            for (int cc = 0; cc < 8; ++cc) {
                float p = fmaf(ef.x, wv[cc][0], bb[cc]);
                p = fmaf(ef.y, wv[cc][1], p);
                p = fmaf(ef.z, wv[cc][2], p);
                p = fmaf(ef.w, wv[cc][3], p);
                p = fmaf(eg.x, wv[cc][4], p);
                p = fmaf(eg.y, wv[cc][5], p);
                p = fmaxf(p, 0.f);
                acc[cc] = fmaf(hv[cc], p, acc[cc]);
            }
        }
        float s = 0.f;
#pragma unroll
        for (int cc = 0; cc < 8; ++cc) s += acc[cc];
        atomicAdd(&agg2[j * C2 + o], s * (1.f / N));
    } else {
        const int c0 = (chunk - 32) * 32;
        float s = 0.f;
#pragma unroll 8
        for (int c = c0; c < c0 + 32; ++c)
            s = fmaf(h1[j * C1 + c], root2[c * C2 + o], s);
        atomicAdd(&agg2[j * C2 + o], s);
    }
}

__global__ __launch_bounds__(256) void k_l3(
    const float* __restrict__ ea,
    const float* __restrict__ w3, const float* __restrict__ b3,
    const float* __restrict__ agg2, const float* __restrict__ bias2,
    const float* __restrict__ root3,
    float* __restrict__ agg3)
{
    const int j     = blockIdx.x % N;
    const int chunk = blockIdx.x / N;
    const int tid   = threadIdx.x;
    const int o     = tid & (C3 - 1);
    const int half  = tid >> 7;

    if (chunk < 32) {
        const int c0 = chunk * 8;
        __shared__ float ea_s[N * 8];
        __shared__ float h2_s[N * 8];
        if (tid < N * 6) { int i = tid / 6, v = tid % 6; ea_s[i * 8 + v] = ea[(i * N + j) * 6 + v]; }
        for (int t = tid; t < N * 8; t += 256) {
            int i = t >> 3, cc = t & 7;
            int c = c0 + cc;
            h2_s[t] = fmaxf(agg2[i * C2 + c] + bias2[c], 0.f);
        }
        __syncthreads();

        float wv[8][6], bb[8], acc[8];
#pragma unroll
        for (int cc = 0; cc < 8; ++cc) {
            int col = (c0 + cc) * C3 + o;
#pragma unroll
            for (int v = 0; v < 6; ++v) wv[cc][v] = w3[v * (C2 * C3) + col];
            bb[cc] = b3[col];
            acc[cc] = 0.f;
        }
        const int ibeg = half ? 18 : 0;
        const int iend = half ? N  : 18;
        for (int i = ibeg; i < iend; ++i) {
            const float4 ef = *(const float4*)&ea_s[i * 8];
            const float2 eg = *(const float2*)&ea_s[i * 8 + 4];
            const float4 ha = *(const float4*)&h2_s[i * 8];
            const float4 hb = *(const float4*)&h2_s[i * 8 + 4];
            const float hv[8] = {ha.x, ha.y, ha.z, ha.w, hb.x, hb.y, hb.z, hb.w};
#pragma unroll
            for (int cc = 0; cc < 8; ++cc) {
                float p = fmaf(ef.x, wv[cc][0], bb[cc]);
                p = fmaf(ef.y, wv[cc][1], p);
                p = fmaf(ef.z, wv[cc][2], p);
                p = fmaf(ef.w, wv[cc][3], p);
                p = fmaf(eg.x, wv[cc][4], p);
                p = fmaf(eg.y, wv[cc][5], p);
                p = fmaxf(p, 0.f);
                acc[cc] = fmaf(hv[cc], p, acc[cc]);
            }
        }
        float s = 0.f;
#pragma unroll
        for (int cc = 0; cc < 8; ++cc) s += acc[cc];
        atomicAdd(&agg3[j * C3 + o], s * (1.f / N));
    } else {
        const int c0 = (chunk - 32) * 64 + half * 32;
        float s = 0.f;
#pragma unroll 8
        for (int c = c0; c < c0 + 32; ++c) {
            float hv = fmaxf(agg2[j * C2 + c] + bias2[c], 0.f);
            s = fmaf(hv, root3[c * C3 + o], s);
        }
        atomicAdd(&agg3[j * C3 + o], s);
    }
}

__global__ __launch_bounds__(256) void k_cbt(
    const float* __restrict__ agg3, const float* __restrict__ bias3,
    float* __restrict__ out)
{
    int t = blockIdx.x * 256 + threadIdx.x;
    if (t >= E) return;
    int i = t / N, j = t % N;
    float acc = 0.f;
#pragma unroll
    for (int f = 0; f < C3 / 4; ++f) {
        float4 a  = *(const float4*)&agg3[i * C3 + f * 4];
        float4 b  = *(const float4*)&agg3[j * C3 + f * 4];
        float4 bi = *(const float4*)&bias3[f * 4];
        float ax = fmaxf(a.x + bi.x, 0.f), bx = fmaxf(b.x + bi.x, 0.f);
        float ay = fmaxf(a.y + bi.y, 0.f), by = fmaxf(b.y + bi.y, 0.f);
        float az = fmaxf(a.z + bi.z, 0.f), bz = fmaxf(b.z + bi.z, 0.f);
        float aw = fmaxf(a.w + bi.w, 0.f), bw = fmaxf(b.w + bi.w, 0.f);
        acc += fabsf(bx - ax) + fabsf(by - ay) + fabsf(bz - az) + fabsf(bw - aw);
    }
    out[t] = acc;
}

extern "C" void kernel_launch(void* const* d_in, const int* in_sizes, int n_in,
                              void* d_out, int out_size, void* d_ws, size_t ws_size,
                              hipStream_t stream)
{
    const float* x     = (const float*)d_in[0];
    const float* ea    = (const float*)d_in[1];
    // d_in[2] = edge_index, unused: topology is static (src=e/35, dst=e%35)
    const float* nn1w  = (const float*)d_in[3];
    const float* nn1b  = (const float*)d_in[4];
    const float* nn2w  = (const float*)d_in[5];
    const float* nn2b  = (const float*)d_in[6];
    const float* nn3w  = (const float*)d_in[7];
    const float* nn3b  = (const float*)d_in[8];
    const float* root1 = (const float*)d_in[9];
    const float* bias1 = (const float*)d_in[10];
    const float* root2 = (const float*)d_in[11];
    const float* bias2 = (const float*)d_in[12];
    const float* root3 = (const float*)d_in[13];
    const float* bias3 = (const float*)d_in[14];

    float* ws   = (float*)d_ws;
    float* h1   = ws;
    float* agg2 = ws + 8960;
    float* agg3 = ws + 8960 + 8960;
    float* out  = (float*)d_out;

    void* args[] = {
        (void*)&x, (void*)&ea, (void*)&nn1w, (void*)&nn1b,
        (void*)&nn2w, (void*)&nn2b, (void*)&nn3w, (void*)&nn3b,
        (void*)&root1, (void*)&bias1, (void*)&root2, (void*)&bias2,
        (void*)&root3, (void*)&bias3,
        (void*)&h1, (void*)&agg2, (void*)&agg3, (void*)&out
    };
    hipError_t err = hipLaunchCooperativeKernel((void*)k_fused, dim3(NBLK), dim3(NTHR),
                                                args, 0, stream);
    if (err != hipSuccess) {
        // deterministic fallback: proven 4-kernel path
        k_layer1<<<N, C1, 0, stream>>>(x, ea, nn1w, nn1b, root1, bias1, h1, agg2);
        k_l2<<<N * 40, 256, 0, stream>>>(ea, nn2w, nn2b, h1, root2, agg2);
        k_l3<<<N * 36, 256, 0, stream>>>(ea, nn3w, nn3b, agg2, bias2, root3, agg3);
        k_cbt<<<(E + 255) / 256, 256, 0, stream>>>(agg3, bias3, out);
    }
}

// Round 7
// 36.542 us; speedup vs baseline: 5.2051x; 5.2051x over previous
//
#include <hip/hip_runtime.h>

#define N  35
#define E  (N*N)
#define C1 256
#define C2 256
#define C3 128

// Workspace layout (floats):
//   h1   @ 0     : 35*256 = 8960
//   agg2 @ 8960  : 35*256 = 8960   (accumulators, zeroed by k_layer1 each call;
//   agg3 @ 17920 : 35*128 = 4480    hold PRE-activation. bias+relu applied at read.)

// ---------------- Layer 1: cin=1, cout=256 (also zeroes agg2/agg3) ----------------
__global__ __launch_bounds__(C1) void k_layer1(
    const float* __restrict__ x, const float* __restrict__ ea,
    const float* __restrict__ nn1w, const float* __restrict__ nn1b,
    const float* __restrict__ root1, const float* __restrict__ bias1,
    float* __restrict__ h1, float* __restrict__ aggz)
{
    const int j = blockIdx.x;
    const int o = threadIdx.x;

    // zero agg2+agg3 (13440 floats = 3360 float4) across the grid, float4 stores
    {
        int t = blockIdx.x * C1 + threadIdx.x;
        if (t < 3360) {
            float4 z; z.x = z.y = z.z = z.w = 0.f;
            ((float4*)aggz)[t] = z;
        }
    }

    __shared__ float ea_s[N * 8];   // edges with dst=j, row-padded to 8
    if (o < N * 6) { int i = o / 6, v = o % 6; ea_s[i * 8 + v] = ea[(i * N + j) * 6 + v]; }
    __syncthreads();

    float w[6];
#pragma unroll
    for (int v = 0; v < 6; ++v) w[v] = nn1w[v * C1 + o];
    const float b = nn1b[o];
    float acc = 0.f;
#pragma unroll 7
    for (int i = 0; i < N; ++i) {
        const float4 ef = *(const float4*)&ea_s[i * 8];
        const float2 eg = *(const float2*)&ea_s[i * 8 + 4];
        float p = fmaf(ef.x, w[0], b);
        p = fmaf(ef.y, w[1], p);
        p = fmaf(ef.z, w[2], p);
        p = fmaf(ef.w, w[3], p);
        p = fmaf(eg.x, w[4], p);
        p = fmaf(eg.y, w[5], p);
        acc = fmaf(x[i], fmaxf(p, 0.f), acc);
    }
    float s = acc * (1.f / N) + x[j] * root1[o] + bias1[o];
    h1[j * C1 + o] = fmaxf(s, 0.f);
}

// ---------------- Layer 2: 64 msg chunks (4c) + 8 root chunks (32c) ----------------
__global__ __launch_bounds__(256) void k_l2(
    const float* __restrict__ ea,
    const float* __restrict__ w2, const float* __restrict__ b2,
    const float* __restrict__ h1, const float* __restrict__ root2,
    float* __restrict__ agg2)
{
    const int j     = blockIdx.x % N;
    const int chunk = blockIdx.x / N;   // 0..71
    const int o     = threadIdx.x;

    if (chunk < 64) {
        const int c0 = chunk * 4;
        __shared__ float ea_s[N * 8];
        __shared__ float h_s[N * 4];
        if (o < N * 6) { int i = o / 6, v = o % 6; ea_s[i * 8 + v] = ea[(i * N + j) * 6 + v]; }
        if (o < N * 4) { int i = o >> 2, cc = o & 3; h_s[o] = h1[i * C1 + c0 + cc]; }
        __syncthreads();

        float wv[4][6], bb[4], acc[4];
#pragma unroll
        for (int cc = 0; cc < 4; ++cc) {
            int col = (c0 + cc) * C2 + o;
#pragma unroll
            for (int v = 0; v < 6; ++v) wv[cc][v] = w2[v * (C1 * C2) + col];
            bb[cc] = b2[col];
            acc[cc] = 0.f;
        }
#pragma unroll 7
        for (int i = 0; i < N; ++i) {
            const float4 ef = *(const float4*)&ea_s[i * 8];
            const float2 eg = *(const float2*)&ea_s[i * 8 + 4];
            const float4 h4 = *(const float4*)&h_s[i * 4];
            const float hv[4] = {h4.x, h4.y, h4.z, h4.w};
#pragma unroll
            for (int cc = 0; cc < 4; ++cc) {
                float p = fmaf(ef.x, wv[cc][0], bb[cc]);
                p = fmaf(ef.y, wv[cc][1], p);
                p = fmaf(ef.z, wv[cc][2], p);
                p = fmaf(ef.w, wv[cc][3], p);
                p = fmaf(eg.x, wv[cc][4], p);
                p = fmaf(eg.y, wv[cc][5], p);
                p = fmaxf(p, 0.f);
                acc[cc] = fmaf(hv[cc], p, acc[cc]);
            }
        }
        float s = (acc[0] + acc[1]) + (acc[2] + acc[3]);
        atomicAdd(&agg2[j * C2 + o], s * (1.f / N));
    } else {
        // root contribution: 32 c's per chunk (8 chunks cover 256)
        const int c0 = (chunk - 64) * 32;
        float s = 0.f;
#pragma unroll 8
        for (int c = c0; c < c0 + 32; ++c)
            s = fmaf(h1[j * C1 + c], root2[c * C2 + o], s);
        atomicAdd(&agg2[j * C2 + o], s);
    }
}

// ---------------- Layer 3: 64 msg chunks (4c) + 4 root chunks (64c) ----------------
// h2(i,c) = relu(agg2[i,c] + bias2[c]) computed on the fly.
__global__ __launch_bounds__(256) void k_l3(
    const float* __restrict__ ea,
    const float* __restrict__ w3, const float* __restrict__ b3,
    const float* __restrict__ agg2, const float* __restrict__ bias2,
    const float* __restrict__ root3,
    float* __restrict__ agg3)
{
    const int j     = blockIdx.x % N;
    const int chunk = blockIdx.x / N;   // 0..67
    const int tid   = threadIdx.x;
    const int o     = tid & (C3 - 1);
    const int half  = tid >> 7;         // wave-uniform

    if (chunk < 64) {
        const int c0 = chunk * 4;
        __shared__ float ea_s[N * 8];
        __shared__ float h2_s[N * 4];
        if (tid < N * 6) { int i = tid / 6, v = tid % 6; ea_s[i * 8 + v] = ea[(i * N + j) * 6 + v]; }
        if (tid < N * 4) {
            int i = tid >> 2, cc = tid & 3;
            int c = c0 + cc;
            h2_s[tid] = fmaxf(agg2[i * C2 + c] + bias2[c], 0.f);
        }
        __syncthreads();

        float wv[4][6], bb[4], acc[4];
#pragma unroll
        for (int cc = 0; cc < 4; ++cc) {
            int col = (c0 + cc) * C3 + o;
#pragma unroll
            for (int v = 0; v < 6; ++v) wv[cc][v] = w3[v * (C2 * C3) + col];
            bb[cc] = b3[col];
            acc[cc] = 0.f;
        }
        const int ibeg = half ? 18 : 0;
        const int iend = half ? N  : 18;
        for (int i = ibeg; i < iend; ++i) {
            const float4 ef = *(const float4*)&ea_s[i * 8];
            const float2 eg = *(const float2*)&ea_s[i * 8 + 4];
            const float4 h4 = *(const float4*)&h2_s[i * 4];
            const float hv[4] = {h4.x, h4.y, h4.z, h4.w};
#pragma unroll
            for (int cc = 0; cc < 4; ++cc) {
                float p = fmaf(ef.x, wv[cc][0], bb[cc]);
                p = fmaf(ef.y, wv[cc][1], p);
                p = fmaf(ef.z, wv[cc][2], p);
                p = fmaf(ef.w, wv[cc][3], p);
                p = fmaf(eg.x, wv[cc][4], p);
                p = fmaf(eg.y, wv[cc][5], p);
                p = fmaxf(p, 0.f);
                acc[cc] = fmaf(hv[cc], p, acc[cc]);
            }
        }
        float s = (acc[0] + acc[1]) + (acc[2] + acc[3]);
        atomicAdd(&agg3[j * C3 + o], s * (1.f / N));
    } else {
        // root contribution: 64 c's per chunk, 32 per half (4 chunks cover 256)
        const int c0 = (chunk - 64) * 64 + half * 32;
        float s = 0.f;
#pragma unroll 8
        for (int c = c0; c < c0 + 32; ++c) {
            float hv = fmaxf(agg2[j * C2 + c] + bias2[c], 0.f);
            s = fmaf(hv, root3[c * C3 + o], s);
        }
        atomicAdd(&agg3[j * C3 + o], s);
    }
}

// ---------------- CBT: pairwise L1 distance, h3 staged in LDS ----------------
#define H3PAD 132   // row pad: 132 % 32 = 4 banks -> rotates start bank per row
__global__ __launch_bounds__(256) void k_cbt(
    const float* __restrict__ agg3, const float* __restrict__ bias3,
    float* __restrict__ out)
{
    __shared__ float h3s[N * H3PAD];
    const int tid = threadIdx.x;
    // stage all of h3 = relu(agg3 + bias3): 4480 loads, coalesced
    for (int t = tid; t < N * C3; t += 256) {
        int i = t >> 7, f = t & (C3 - 1);
        h3s[i * H3PAD + f] = fmaxf(agg3[t] + bias3[f], 0.f);
    }
    __syncthreads();

    int t = blockIdx.x * 256 + tid;
    if (t >= E) return;
    int i = t / N, j = t % N;
    const float* hi = &h3s[i * H3PAD];
    const float* hj = &h3s[j * H3PAD];
    float acc = 0.f;
#pragma unroll
    for (int f = 0; f < C3 / 4; ++f) {
        float4 a = *(const float4*)&hi[f * 4];
        float4 b = *(const float4*)&hj[f * 4];
        acc += fabsf(b.x - a.x) + fabsf(b.y - a.y) + fabsf(b.z - a.z) + fabsf(b.w - a.w);
    }
    out[t] = acc;
}

extern "C" void kernel_launch(void* const* d_in, const int* in_sizes, int n_in,
                              void* d_out, int out_size, void* d_ws, size_t ws_size,
                              hipStream_t stream)
{
    const float* x     = (const float*)d_in[0];
    const float* ea    = (const float*)d_in[1];
    // d_in[2] = edge_index, unused: topology is static (src=e/35, dst=e%35)
    const float* nn1w  = (const float*)d_in[3];
    const float* nn1b  = (const float*)d_in[4];
    const float* nn2w  = (const float*)d_in[5];
    const float* nn2b  = (const float*)d_in[6];
    const float* nn3w  = (const float*)d_in[7];
    const float* nn3b  = (const float*)d_in[8];
    const float* root1 = (const float*)d_in[9];
    const float* bias1 = (const float*)d_in[10];
    const float* root2 = (const float*)d_in[11];
    const float* bias2 = (const float*)d_in[12];
    const float* root3 = (const float*)d_in[13];
    const float* bias3 = (const float*)d_in[14];

    float* ws   = (float*)d_ws;
    float* h1   = ws;
    float* agg2 = ws + 8960;
    float* agg3 = ws + 8960 + 8960;

    k_layer1<<<N, C1, 0, stream>>>(x, ea, nn1w, nn1b, root1, bias1, h1, agg2);
    k_l2<<<N * 72, 256, 0, stream>>>(ea, nn2w, nn2b, h1, root2, agg2);
    k_l3<<<N * 68, 256, 0, stream>>>(ea, nn3w, nn3b, agg2, bias2, root3, agg3);
    k_cbt<<<(E + 255) / 256, 256, 0, stream>>>(agg3, bias3, (float*)d_out);
}